// Round 12
// baseline (67.040 us; speedup 1.0000x reference)
//
#include <hip/hip_runtime.h>

// ---------------------------------------------------------------------------
// SNN Perceptron Equalizer (LIF recurrent net), MI355X
//
//  * ff = xt@W_in^T  ->  <=3 precomputed rows P[t][seg][sym][h] (fp64-built).
//  * One WAVE per batch element; lane l holds h=4l..4l+3 (f32x4 state).
//    1024 blocks x 256 threads (4 indep waves) -> 16 waves/CU.
//    launch_bounds(256,4): full 128-VGPR budget (grid caps occupancy anyway).
//  * R5's PROVEN step schedule (spike from old cur; cur=(0.8cur+ff_t)+rec(z_{t-1}))
//    with EIGHT WT slots (c_bar ~ 8) issued via asm-volatile
//    global_load_dwordx4 (unsinkable by regalloc), drained once per iter by
//    s_waitcnt vmcnt(0) + sched_barrier(0)  (rule #18). Peels are SALU,
//    done BEFORE the drain. Dummy slots hit the zero row (L1-hot, +0 exact).
//    Overflow c>8 (rare) summed synchronously, consumed next iter.
//  * z_sum[b,:] = 32*b_out + sum_h cnt[b,h]*W_out[:,h]; rate = spikes/2^25.
// ---------------------------------------------------------------------------

typedef float f32x4 __attribute__((ext_vector_type(4)));

#define T_STEPS 32
#define FDIM    41
#define ODIM    16
#define BDIM    4096
#define MF      164

#define P_FLOATS   (32 * 3 * 16 * 256)
#define WT_ROWS    257                  // row 256 = zeros (dummy target)
#define WT_FLOATS  (WT_ROWS * 256)

#define HAS3(T) ((((T) * MF) & 127) > 92)

__device__ __forceinline__ f32x4 gload(const f32x4* p) {
    f32x4 r;
    asm volatile("global_load_dwordx4 %0, %1, off" : "=&v"(r) : "v"(p));
    return r;
}

// ---------------------------------------------------------------------------
// K1: build P (fp64 accum; 4-symbol groups), transpose W_rec (+zero row),
//     zero spike counter.  blocks 0..383: P; 384..640: W_rec^T.
// ---------------------------------------------------------------------------
__global__ __launch_bounds__(256) void k_prep(const float* __restrict__ emb,
                                              const float* __restrict__ W_in,
                                              const float* __restrict__ W_rec,
                                              float* __restrict__ P,
                                              float* __restrict__ WT,
                                              int* __restrict__ counter)
{
    const int bid = blockIdx.x;
    const int tid = threadIdx.x;

    if (bid < 384) {
        const int g  = bid & 3;
        const int ts = bid >> 2;
        const int t  = ts / 3;
        const int si = ts % 3;
        const int k0   = t * MF;
        const int f    = (k0 >> 7) + si;
        const int base = f << 7;
        const int c0   = max(k0, base) - base;
        const int c1   = min(k0 + MF, base + 128) - base;
        const int len  = c1 - c0;

        if (len <= 0) {
            #pragma unroll
            for (int s = 0; s < 4; ++s)
                P[((t * 3 + si) * 16 + 4 * g + s) * 256 + tid] = 0.0f;
            return;
        }

        __shared__ float emb_lds[4][128];
        for (int idx = tid; idx < 4 * 128; idx += 256) {
            const int s = idx >> 7, u = idx & 127;
            if (u < len) emb_lds[s][u] = emb[((4 * g + s) << 7) + c0 + u];
        }
        __syncthreads();

        const int j0 = base + c0 - k0;
        double a0 = 0.0, a1 = 0.0, a2 = 0.0, a3 = 0.0;
        for (int u = 0; u < len; ++u) {
            const double w = (double)W_in[tid * MF + j0 + u];
            a0 += w * (double)emb_lds[0][u];
            a1 += w * (double)emb_lds[1][u];
            a2 += w * (double)emb_lds[2][u];
            a3 += w * (double)emb_lds[3][u];
        }
        P[((t * 3 + si) * 16 + 4 * g + 0) * 256 + tid] = (float)a0;
        P[((t * 3 + si) * 16 + 4 * g + 1) * 256 + tid] = (float)a1;
        P[((t * 3 + si) * 16 + 4 * g + 2) * 256 + tid] = (float)a2;
        P[((t * 3 + si) * 16 + 4 * g + 3) * 256 + tid] = (float)a3;
    } else {
        const int h = bid - 384;                // 0..256
        if (h < 256) {
            WT[h * 256 + tid] = W_rec[tid * 256 + h];
        } else {
            WT[256 * 256 + tid] = 0.0f;
            if (tid == 0) *counter = 0;
        }
    }
}

// ---------------------------------------------------------------------------
// K2: main LIF scan. 1024 blocks x 256 threads (4 indep waves / block).
// ---------------------------------------------------------------------------
__global__ __launch_bounds__(256, 4) void k_main(const int* __restrict__ x,
                                                 const float* __restrict__ P,
                                                 const float* __restrict__ WT,
                                                 const float* __restrict__ W_out,
                                                 const float* __restrict__ b_out,
                                                 float* __restrict__ out,
                                                 int* __restrict__ counter)
{
#pragma clang fp contract(off)
    __shared__ float cnt_lds[4][256];
    __shared__ int   red[4];

    const int tid  = threadIdx.x;
    const int lane = tid & 63;
    const int wv   = __builtin_amdgcn_readfirstlane(tid >> 6);
    const int b    = blockIdx.x * 4 + wv;

    const f32x4* __restrict__ P4  = (const f32x4*)P;
    const f32x4* __restrict__ WT4 = (const f32x4*)WT;

    const int xv = (lane < FDIM) ? x[b * FDIM + lane] : 0;

    const f32x4 zero4 = {0.f, 0.f, 0.f, 0.f};
    f32x4 vm = zero4;          // membrane v
    f32x4 cur = zero4;         // synaptic current i
    f32x4 rext = zero4;        // overflow rec (consumed next iter)
    f32x4 s0 = zero4, s1 = zero4, s2 = zero4, s3 = zero4,
          s4 = zero4, s5 = zero4, s6 = zero4, s7 = zero4;   // pinned slots
    f32x4 pf0 = zero4, pf1 = zero4, pf2 = zero4;            // pinned P rows
    int cg = 0;                // slot count of the generation in flight
    int n0 = 0, n1 = 0, n2 = 0, n3 = 0;

    // prologue: P rows for t=0 (2 segments at t=0)
    pf0 = gload(P4 + (0 * 16 + __builtin_amdgcn_readlane(xv, 0)) * 64 + lane);
    pf1 = gload(P4 + (1 * 16 + __builtin_amdgcn_readlane(xv, 1)) * 64 + lane);

    // peel one spiking unit id from masks h0..h3 (uniform SALU); dst keeps
    // its dummy value (row 256 = zeros) when all masks are empty.
    #define PEEL(dst)                                                          \
        if (h0)      { dst = 4*(int)__builtin_ctzll(h0)+0; h0 &= h0-1; }       \
        else if (h1) { dst = 4*(int)__builtin_ctzll(h1)+1; h1 &= h1-1; }       \
        else if (h2) { dst = 4*(int)__builtin_ctzll(h2)+2; h2 &= h2-1; }       \
        else if (h3) { dst = 4*(int)__builtin_ctzll(h3)+3; h3 &= h3-1; }

    #pragma unroll
    for (int t = 0; t < T_STEPS; ++t) {
        // (a) LIF decision from state only (independent of in-flight loads)
        const f32x4 vdec = vm + 0.1f * (cur - vm);
        const bool z0 = vdec.x > 1.0f, z1 = vdec.y > 1.0f,
                   z2 = vdec.z > 1.0f, z3 = vdec.w > 1.0f;
        const unsigned long long m0 = __ballot(z0), m1 = __ballot(z1),
                                 m2 = __ballot(z2), m3 = __ballot(z3);
        vm.x = z0 ? 0.0f : vdec.x;  vm.y = z1 ? 0.0f : vdec.y;
        vm.z = z2 ? 0.0f : vdec.z;  vm.w = z3 ? 0.0f : vdec.w;
        n0 += z0; n1 += z1; n2 += z2; n3 += z3;

        // peel up to 8 ids for z_t (SALU, overlaps the in-flight loads)
        unsigned long long h0 = m0, h1 = m1, h2 = m2, h3 = m3;
        const int cg_ = __popcll(h0) + __popcll(h1)
                      + __popcll(h2) + __popcll(h3);
        int ua = 256, ub = 256, uc = 256, ud = 256,
            ue = 256, uf = 256, ug = 256, uh = 256;
        PEEL(ua) PEEL(ub) PEEL(uc) PEEL(ud)
        PEEL(ue) PEEL(uf) PEEL(ug) PEEL(uh)

        // (b) single drain point for everything issued last iteration
        asm volatile("s_waitcnt vmcnt(0)" ::: "memory");
        __builtin_amdgcn_sched_barrier(0);

        // (c) consume: rec(z_{t-1}) + ff_t ; update current  (ref order)
        f32x4 rec = rext;
        if (cg > 0) { rec += s0; rec += s1; }
        if (cg > 2) { rec += s2; rec += s3; }
        if (cg > 4) { rec += s4; rec += s5; }
        if (cg > 6) { rec += s6; rec += s7; }
        f32x4 ff = pf0 + pf1;
        if (HAS3(t)) ff += pf2;
        cur = (cur * 0.8f + ff) + rec;

        // (d) issue next generation
        if (t + 1 < T_STEPS) {
            // overflow first (regular loads; compiler-managed waits)
            rext = zero4;
            while (h0) { const int r = 4*(int)__builtin_ctzll(h0)+0; h0 &= h0-1;
                         rext += WT4[r * 64 + lane]; }
            while (h1) { const int r = 4*(int)__builtin_ctzll(h1)+1; h1 &= h1-1;
                         rext += WT4[r * 64 + lane]; }
            while (h2) { const int r = 4*(int)__builtin_ctzll(h2)+2; h2 &= h2-1;
                         rext += WT4[r * 64 + lane]; }
            while (h3) { const int r = 4*(int)__builtin_ctzll(h3)+3; h3 &= h3-1;
                         rext += WT4[r * 64 + lane]; }

            // pinned WT slot loads for z_t (consumed at t+1)
            if (cg_ > 0) { s0 = gload(WT4 + ua * 64 + lane);
                           s1 = gload(WT4 + ub * 64 + lane); }
            if (cg_ > 2) { s2 = gload(WT4 + uc * 64 + lane);
                           s3 = gload(WT4 + ud * 64 + lane); }
            if (cg_ > 4) { s4 = gload(WT4 + ue * 64 + lane);
                           s5 = gload(WT4 + uf * 64 + lane); }
            if (cg_ > 6) { s6 = gload(WT4 + ug * 64 + lane);
                           s7 = gload(WT4 + uh * 64 + lane); }
            cg = cg_;

            // pinned P rows for t+1
            const int tn = t + 1;
            const int f0 = (tn * MF) >> 7;
            pf0 = gload(P4 + ((tn*3 + 0)*16 + __builtin_amdgcn_readlane(xv, f0    )) * 64 + lane);
            pf1 = gload(P4 + ((tn*3 + 1)*16 + __builtin_amdgcn_readlane(xv, f0 + 1)) * 64 + lane);
            if (HAS3(tn))
                pf2 = gload(P4 + ((tn*3 + 2)*16 + __builtin_amdgcn_readlane(xv, f0 + 2)) * 64 + lane);
        }
    }
    #undef PEEL

    // --- publish per-h spike counts & block spike total ---
    cnt_lds[wv][4 * lane + 0] = (float)n0;
    cnt_lds[wv][4 * lane + 1] = (float)n1;
    cnt_lds[wv][4 * lane + 2] = (float)n2;
    cnt_lds[wv][4 * lane + 3] = (float)n3;

    int myspk = n0 + n1 + n2 + n3;
    #pragma unroll
    for (int off = 32; off > 0; off >>= 1)
        myspk += __shfl_down(myspk, off, 64);
    if (lane == 0) red[wv] = myspk;

    __syncthreads();
    if (tid == 0) atomicAdd(counter, red[0] + red[1] + red[2] + red[3]);

    // --- epilogue: z_sum[b,o] = 32*b_out[o] + sum_h cnt[h]*W_out[o,h] ---
    {
        const int o = lane & 15;
        const int q = lane >> 4;
        const float* __restrict__ wo = W_out + o * 256 + q * 64;
        const float* __restrict__ cl = cnt_lds[wv] + q * 64;
        float acc = 0.0f;
        #pragma unroll 8
        for (int h = 0; h < 64; ++h)
            acc += cl[h] * wo[h];
        acc += __shfl_down(acc, 16, 64);
        acc += __shfl_down(acc, 32, 64);
        if (q == 0)
            out[b * ODIM + o] = 32.0f * b_out[o] + acc;
    }
}

// ---------------------------------------------------------------------------
// K3: spikerate = count / 2^25 (exact in fp32 since count < 2^24)
// ---------------------------------------------------------------------------
__global__ void k_fin(const int* __restrict__ counter, float* __restrict__ out)
{
    out[BDIM * ODIM] = (float)(*counter) * (1.0f / 33554432.0f);
}

// ---------------------------------------------------------------------------
extern "C" void kernel_launch(void* const* d_in, const int* in_sizes, int n_in,
                              void* d_out, int out_size, void* d_ws, size_t ws_size,
                              hipStream_t stream)
{
    const int*   x     = (const int*)  d_in[0];
    const float* emb   = (const float*)d_in[1];
    const float* W_in  = (const float*)d_in[2];
    const float* W_rec = (const float*)d_in[3];
    const float* W_out = (const float*)d_in[4];
    const float* b_out = (const float*)d_in[5];
    float* out = (float*)d_out;

    float* P       = (float*)d_ws;
    float* WT      = P + P_FLOATS;
    int*   counter = (int*)(WT + WT_FLOATS);

    k_prep<<<384 + 257, 256, 0, stream>>>(emb, W_in, W_rec, P, WT, counter);
    k_main<<<BDIM / 4, 256, 0, stream>>>(x, P, WT, W_out, b_out, out, counter);
    k_fin<<<1, 1, 0, stream>>>(counter, out);
}